// Round 6
// baseline (254.289 us; speedup 1.0000x reference)
//
#include <hip/hip_runtime.h>
#include <hip/hip_fp16.h>
#include <math.h>

#define N_NODES 50000
#define N_EDGES 800000
#define VOCAB 100
#define DIM 128
#define N_GRAPHS 512
#define LN_EPS 1e-5f
#define CAP 64    // slot capacity per node (deg~Poisson(16); P(>=64)~e^-125)
#define SEG 4     // nodes per wave in k_agg2 (50000 % 4 == 0)
#define NWIN 8    // dst windows (== XCDs)
#define WSZ ((N_NODES + NWIN - 1) / NWIN)
#define NSCAT 2048               // scatter blocks (multiple of 8)
#define NE4 (N_EDGES / 4)        // 200000 int4 edge chunks (exact)
#define CPAD 8    // cnt padding stride (ints): 32 B/counter

using bf16x8  = __attribute__((ext_vector_type(8))) __bf16;
using floatx4 = __attribute__((ext_vector_type(4))) float;

__device__ __forceinline__ unsigned short f2bf(float f) {
    unsigned u = __float_as_uint(f);
    return (unsigned short)((u + 0x7FFF + ((u >> 16) & 1)) >> 16);  // RNE
}

// ---------------- scatter (XCD-windowed, int4 dst scan) + EW1 + starts + out-init ----
__global__ __launch_bounds__(256) void k_scatter(const int* __restrict__ src,
                                                 const int* __restrict__ dst,
                                                 const int* __restrict__ batch,
                                                 const float* __restrict__ emb,
                                                 const float* __restrict__ W1,
                                                 const float* __restrict__ fcb,
                                                 int* __restrict__ cnt,
                                                 int* __restrict__ slots,
                                                 float* __restrict__ EW1,
                                                 int* __restrict__ starts,
                                                 float* __restrict__ out) {
    int t = threadIdx.x;
    if (blockIdx.x < NSCAT) {
        int w = blockIdx.x & (NWIN - 1);
        int bg = blockIdx.x >> 3;
        int lo = w * WSZ, hi = lo + WSZ; if (hi > N_NODES) hi = N_NODES;
        int stride = (NSCAT >> 3) * 256;  // 65536 threads per window group
        for (int e4 = bg * 256 + t; e4 < NE4; e4 += stride) {
            int4 d4 = ((const int4*)dst)[e4];
            int e = e4 * 4;
            #pragma unroll
            for (int c = 0; c < 4; c++) {
                int d = (&d4.x)[c];
                if (d >= lo && d < hi) {
                    int pos = atomicAdd(&cnt[d * CPAD], 1);
                    slots[d * CAP + pos] = src[e + c];
                }
            }
        }
    } else if (blockIdx.x < NSCAT + 50) {
        int idx = (blockIdx.x - NSCAT) * 256 + t;   // < 12800 always
        int r = idx >> 7, c = idx & 127;
        float acc = 0.f;
        for (int k = 0; k < DIM; k++) acc += emb[r * DIM + k] * W1[k * DIM + c];
        EW1[idx] = acc;
    } else {
        for (int g = t; g <= N_GRAPHS; g += 256) {
            int lo = 0, hi = N_NODES;
            while (lo < hi) { int mid = (lo + hi) >> 1; if (batch[mid] < g) lo = mid + 1; else hi = mid; }
            starts[g] = lo;
        }
        float fb = fcb[0];
        for (int g = t; g < N_GRAPHS; g += 256) out[g] = fb;
    }
}

// ---------------- layer-1 agg + one-pass LN + ReLU, cross-node pipelined ----------------
// Output rows PRE-SCALED by dinv_i: h1b[i] = bf16(dinv_i * h1_i), so layer-2
// aggregation is a pure row-sum (associativity: A_hat (h1 W2) == (A_hat h1) W2).
__global__ __launch_bounds__(512) void k_agg1(
    const float* __restrict__ EW1, const int* __restrict__ x,
    const int* __restrict__ cnt, const int* __restrict__ slots,
    const float* __restrict__ b1, const float* __restrict__ g1,
    const float* __restrict__ be1, unsigned* __restrict__ h1b) {
    __shared__ unsigned ew[VOCAB * 64];  // bf16x2 packed, 25600 B
    for (int idx = threadIdx.x; idx < VOCAB * 64; idx += blockDim.x) {
        float2 v = ((const float2*)EW1)[idx];
        ew[idx] = (unsigned)f2bf(v.x) | ((unsigned)f2bf(v.y) << 16);
    }
    __syncthreads();
    int lane = threadIdx.x & 63;
    int wave = (blockIdx.x * blockDim.x + threadIdx.x) >> 6;
    int nw = (gridDim.x * blockDim.x) >> 6;
    float2 bb = make_float2(b1[2 * lane], b1[2 * lane + 1]);
    float2 gg = make_float2(g1[2 * lane], g1[2 * lane + 1]);
    float2 eb = make_float2(be1[2 * lane], be1[2 * lane + 1]);

    int i = wave;
    if (i >= N_NODES) return;

    int cn, xi; float di; unsigned myw;
    {
        int iu = __builtin_amdgcn_readfirstlane(i);
        cn = cnt[iu * CPAD]; di = rsqrtf((float)cn + 1.f); xi = x[iu];
        int s = slots[(size_t)iu * CAP + lane];
        unsigned ss = min((unsigned)s, (unsigned)(N_NODES - 1));
        float ds = rsqrtf((float)cnt[ss * CPAD] + 1.f);
        myw = ((unsigned)__half_as_ushort(__float2half_rn(ds)) << 16) | (unsigned)x[ss];
    }
    while (i < N_NODES) {
        int inext = i + nw;
        int cnN = 0, xiN = 0; float diN = 0.f; unsigned mywN = 0;
        if (inext < N_NODES) {
            int iun = __builtin_amdgcn_readfirstlane(inext);
            cnN = cnt[iun * CPAD]; diN = rsqrtf((float)cnN + 1.f); xiN = x[iun];
            int s = slots[(size_t)iun * CAP + lane];
            unsigned ss = min((unsigned)s, (unsigned)(N_NODES - 1));
            float ds = rsqrtf((float)cnt[ss * CPAD] + 1.f);
            mywN = ((unsigned)__half_as_ushort(__float2half_rn(ds)) << 16) | (unsigned)x[ss];
        }
        int iu = __builtin_amdgcn_readfirstlane(i);
        unsigned e0 = ew[xi * 64 + lane];
        float ax = di * __uint_as_float(e0 << 16);
        float ay = di * __uint_as_float(e0 & 0xFFFF0000u);  // self-loop
        int j = 0;
        for (; j + 8 <= cn; j += 8) {
            #pragma unroll
            for (int u = 0; u < 8; u++) {
                unsigned w = (unsigned)__shfl((int)myw, j + u, 64);
                int xv = (int)(w & 0xFFFFu);
                float ds = __half2float(__ushort_as_half((unsigned short)(w >> 16)));
                unsigned es = ew[xv * 64 + lane];
                ax += ds * __uint_as_float(es << 16);
                ay += ds * __uint_as_float(es & 0xFFFF0000u);
            }
        }
        for (; j < cn; j++) {
            unsigned w = (unsigned)__shfl((int)myw, j, 64);
            int xv = (int)(w & 0xFFFFu);
            float ds = __half2float(__ushort_as_half((unsigned short)(w >> 16)));
            unsigned es = ew[xv * 64 + lane];
            ax += ds * __uint_as_float(es << 16);
            ay += ds * __uint_as_float(es & 0xFFFF0000u);
        }
        float a0 = di * ax + bb.x, a1 = di * ay + bb.y;
        float s = a0 + a1, q = a0 * a0 + a1 * a1;
        #pragma unroll
        for (int m = 1; m < 64; m <<= 1) {
            s += __shfl_xor(s, m, 64);
            q += __shfl_xor(q, m, 64);
        }
        float mu = s * (1.f / 128.f);
        float r = rsqrtf(q * (1.f / 128.f) - mu * mu + LN_EPS);
        float o0 = fmaxf((a0 - mu) * r * gg.x + eb.x, 0.f);
        float o1 = fmaxf((a1 - mu) * r * gg.y + eb.y, 0.f);
        h1b[(size_t)iu * 64 + lane] =
            (unsigned)f2bf(di * o0) | ((unsigned)f2bf(di * o1) << 16);  // pre-scaled
        i = inext; cn = cnN; di = diN; xi = xiN; myw = mywN;
    }
}

// ---------------- layer-2: gather h1b rows + MFMA matvec by W2 + LN + fc -------------
// Per wave: aggregate 4 nodes (fp32), pack bf16 into A-tile rows 0,4,8,12 (LDS,
// group-XOR swizzle), 32x mfma_16x16x32_bf16 vs W2^T (LDS bf16), node n's output
// lands in lane-group n (C row 4n, reg 0) -> 4 parallel 16-lane LN/fc reductions.
__global__ __launch_bounds__(512, 4) void k_agg2(
    const unsigned* __restrict__ h1u, const int* __restrict__ cnt,
    const int* __restrict__ slots, const int* __restrict__ batch,
    const int* __restrict__ starts, const float* __restrict__ W2,
    const float* __restrict__ b2, const float* __restrict__ g2,
    const float* __restrict__ be2, const float* __restrict__ fcW,
    float* __restrict__ out) {
    __shared__ unsigned w2tu[DIM * 64];   // W2^T bf16x2, swizzled, 32 KB
    __shared__ unsigned utile[8][256];    // per-wave 4x128 bf16 agg rows, swizzled, 8 KB
    int t = threadIdx.x;
    // stage W2^T: row n holds W2[:,n]; dword d covers k=2d,2d+1; group-XOR swizzle
    for (int idx = t; idx < DIM * 64; idx += 512) {
        int n = idx >> 6, d = idx & 63;
        float w0 = W2[(2 * d) * DIM + n], w1 = W2[(2 * d + 1) * DIM + n];
        int pos = (n << 6) | ((((d >> 2) ^ (n & 15)) << 2) | (d & 3));
        w2tu[pos] = (unsigned)f2bf(w0) | ((unsigned)f2bf(w1) << 16);
    }
    __syncthreads();

    int lane = t & 63, wv = t >> 6;
    int wave = blockIdx.x * 8 + wv;
    int i0 = wave * SEG;
    if (i0 >= N_NODES) return;
    int m = lane & 15, quad = lane >> 4;

    // per-lane epilogue params at cols m + 16*nt
    float b2v[8], g2v[8], bev[8], fwv[8];
    #pragma unroll
    for (int nt = 0; nt < 8; nt++) {
        int col = m + nt * 16;
        b2v[nt] = b2[col]; g2v[nt] = g2[col]; bev[nt] = be2[col]; fwv[nt] = fcW[col];
    }

    int cv = 0, bv = 0; float dv = 0.f;
    if (lane < SEG) {
        cv = cnt[(i0 + lane) * CPAD]; dv = rsqrtf((float)cv + 1.f); bv = batch[i0 + lane];
    }

    // ---- gather + accumulate 4 nodes -> utile rows 0..3 (node k at row k) ----
    #pragma unroll
    for (int k = 0; k < SEG; k++) {
        int iu = __builtin_amdgcn_readfirstlane(i0 + k);
        int cn = __builtin_amdgcn_readfirstlane(__shfl(cv, k, 64));
        float di = __shfl(dv, k, 64);
        const int* srow = slots + (size_t)iu * CAP;

        int sx[32];
        #pragma unroll
        for (int u = 0; u < 32; u++) sx[u] = srow[u];

        unsigned u0 = h1u[(size_t)iu * 64 + lane];   // self term (pre-scaled row)
        unsigned uvv[32];
        #pragma unroll
        for (int c8 = 0; c8 < 4; c8++) {
            if (cn > c8 * 8) {
                #pragma unroll
                for (int u = 0; u < 8; u++) {
                    int idx = c8 * 8 + u;
                    int s = (idx < cn) ? sx[idx] : 0;
                    uvv[idx] = h1u[(size_t)s * 64 + lane];
                }
            }
        }
        float ax = __uint_as_float(u0 << 16);
        float ay = __uint_as_float(u0 & 0xFFFF0000u);
        #pragma unroll
        for (int c8 = 0; c8 < 4; c8++) {
            if (cn > c8 * 8) {
                #pragma unroll
                for (int u = 0; u < 8; u++) {
                    int idx = c8 * 8 + u;
                    unsigned vv = (idx < cn) ? uvv[idx] : 0u;
                    ax += __uint_as_float(vv << 16);
                    ay += __uint_as_float(vv & 0xFFFF0000u);
                }
            }
        }
        if (cn > 32) {
            for (int j = 32; j < cn; j++) {
                int s = srow[j];
                unsigned vv = h1u[(size_t)s * 64 + lane];
                ax += __uint_as_float(vv << 16);
                ay += __uint_as_float(vv & 0xFFFF0000u);
            }
        }
        // fold dinv_i, pack, store to A-tile row k (lane holds dims 2*lane, 2*lane+1)
        unsigned pk = (unsigned)f2bf(di * ax) | ((unsigned)f2bf(di * ay) << 16);
        utile[wv][(k << 6) | ((((lane >> 2) ^ k) << 2) | (lane & 3))] = pk;
    }
    asm volatile("s_waitcnt lgkmcnt(0)" ::: "memory");  // wave-local LDS visibility
    __builtin_amdgcn_sched_barrier(0);

    // ---- matvec: A (rows 4r = aggregated nodes, rest zero) @ W2 ----
    floatx4 c[8];
    #pragma unroll
    for (int nt = 0; nt < 8; nt++) c[nt] = (floatx4){0.f, 0.f, 0.f, 0.f};
    #pragma unroll
    for (int kk = 0; kk < 4; kk++) {
        bf16x8 a;
        #pragma unroll
        for (int j = 0; j < 8; j++) a[j] = (__bf16)0.f;
        if ((m & 3) == 0) {                 // A row m nonzero only for m = 4r
            int r = m >> 2;
            a = *(const bf16x8*)&utile[wv][(r << 6) | ((((kk * 4 + quad) ^ r) << 2))];
        }
        #pragma unroll
        for (int nt = 0; nt < 8; nt++) {
            int row = nt * 16 + m;          // row & 15 == m
            bf16x8 b = *(const bf16x8*)&w2tu[(row << 6) | (((kk * 4 + quad) ^ m) << 2)];
            c[nt] = __builtin_amdgcn_mfma_f32_16x16x32_bf16(a, b, c[nt], 0, 0, 0);
        }
    }

    // ---- epilogue: node (i0+quad) at C reg 0; LN + fc in parallel 16-lane groups ----
    float s = 0.f, q = 0.f, h2[8];
    #pragma unroll
    for (int nt = 0; nt < 8; nt++) {
        h2[nt] = c[nt][0] + b2v[nt];
        s += h2[nt]; q += h2[nt] * h2[nt];
    }
    #pragma unroll
    for (int msk = 1; msk < 16; msk <<= 1) {
        s += __shfl_xor(s, msk, 64);
        q += __shfl_xor(q, msk, 64);
    }
    float mu = s * (1.f / 128.f);
    float r = rsqrtf(q * (1.f / 128.f) - mu * mu + LN_EPS);
    float z = 0.f;
    #pragma unroll
    for (int nt = 0; nt < 8; nt++) {
        float o = fmaxf((h2[nt] - mu) * r * g2v[nt] + bev[nt], 0.f);
        z += o * fwv[nt];
    }
    #pragma unroll
    for (int msk = 1; msk < 16; msk <<= 1) z += __shfl_xor(z, msk, 64);

    // ---- per-wave flush (node k's z lives in lane group k) ----
    float pz = 0.f;
    int cur_g = __builtin_amdgcn_readfirstlane(__shfl(bv, 0, 64));
    #pragma unroll
    for (int k = 0; k < SEG; k++) {
        float zk = __shfl(z, k * 16, 64);
        int g = __builtin_amdgcn_readfirstlane(__shfl(bv, k, 64));
        if (g != cur_g) {
            if (lane == 0) {
                float cc = (float)(starts[cur_g + 1] - starts[cur_g]);
                if (cc < 1.f) cc = 1.f;
                atomicAdd(&out[cur_g], pz / cc);
            }
            pz = 0.f; cur_g = g;
        }
        pz += zk;
    }
    if (lane == 0) {
        float cc = (float)(starts[cur_g + 1] - starts[cur_g]);
        if (cc < 1.f) cc = 1.f;
        atomicAdd(&out[cur_g], pz / cc);
    }
}

extern "C" void kernel_launch(void* const* d_in, const int* in_sizes, int n_in,
                              void* d_out, int out_size, void* d_ws, size_t ws_size,
                              hipStream_t stream) {
    (void)in_sizes; (void)n_in; (void)out_size; (void)ws_size;
    const int* x    = (const int*)d_in[0];
    const int* src  = (const int*)d_in[1];
    const int* dst  = src + N_EDGES;
    const int* batch = (const int*)d_in[2];
    const float* emb = (const float*)d_in[3];
    const float* W1  = (const float*)d_in[4];
    const float* b1  = (const float*)d_in[5];
    const float* g1  = (const float*)d_in[6];
    const float* be1 = (const float*)d_in[7];
    const float* W2  = (const float*)d_in[8];
    const float* b2  = (const float*)d_in[9];
    const float* g2  = (const float*)d_in[10];
    const float* be2 = (const float*)d_in[11];
    const float* fcW = (const float*)d_in[12];
    const float* fcb = (const float*)d_in[13];
    float* out = (float*)d_out;

    char* wsp = (char*)d_ws;
    size_t off = 0;
    auto alloc = [&](size_t bytes) -> void* {
        void* p = wsp + off;
        off += (bytes + 15) & ~(size_t)15;
        return p;
    };
    // ---- zeroed region ----
    int* cnt = (int*)alloc((size_t)N_NODES * CPAD * 4);  // 1.6 MB line-padded counters
    size_t zero_bytes = off;
    // ---- scratch ----
    int*   slots  = (int*)alloc((size_t)N_NODES * CAP * 4);  // 12.8 MB
    float* EW1    = (float*)alloc(VOCAB * DIM * 4);
    int*   starts = (int*)alloc((N_GRAPHS + 1) * 4);
    unsigned* h1b = (unsigned*)alloc((size_t)N_NODES * DIM * 2);

    hipMemsetAsync(d_ws, 0, zero_bytes, stream);

    k_scatter<<<NSCAT + 50 + 1, 256, 0, stream>>>(src, dst, batch, emb, W1, fcb,
                                                  cnt, slots, EW1, starts, out);
    k_agg1<<<1024, 512, 0, stream>>>(EW1, x, cnt, slots, b1, g1, be1, h1b);
    {
        int nwaves = (N_NODES + SEG - 1) / SEG;          // 12500
        int nblocks = (nwaves + 7) / 8;                  // 1563 blocks, 8 waves each
        k_agg2<<<nblocks, 512, 0, stream>>>(h1b, cnt, slots, batch, starts,
                                            W2, b2, g2, be2, fcW, out);
    }
}